// Round 5
// baseline (538.904 us; speedup 1.0000x reference)
//
#include <hip/hip_runtime.h>
#include <cstdint>
#include <cmath>

// Problem dims
#define B_   128
#define N_   196
#define D_   768
#define H_   3072
#define R_   384
#define TOK  (B_*N_)      // 25088

typedef int i32x4 __attribute__((ext_vector_type(4)));

// async global->LDS, 16B per lane; LDS dest = wave-uniform base + lane*16
#define GLDS16(g, l) __builtin_amdgcn_global_load_lds( \
    (const __attribute__((address_space(1))) void*)(g), \
    (__attribute__((address_space(3))) void*)(l), 16, 0, 0)

// ---------------- workspace layout (bytes) ----------------
#define OFF_AMAX   0L
#define OFF_LUT    512L                  // 256-entry int8 GELU LUT
#define OFF_QVEC   1024L                 // 6 x 768 fp32 precomputed epilogue vectors
#define OFF_WQA    (32L*1024)            // attn weight int8 padded [256][256]
#define OFF_W1VT   (128L*1024)           // [384][768]
#define OFF_W1U    (512L*1024)           // [3072][384]
#define OFF_W2VT   (2L*1024*1024)        // [384][3072]
#define OFF_W2U    (3328L*1024)          // [768][384]
#define OFF_X1Q    (4L*1024*1024)        // int8 [25088][768]
#define OFF_A4     (24L*1024*1024)       // int8 [25088][384]
#define OFF_A7     (34L*1024*1024)       // int8 [25088][384]
#define OFF_A0T    (44L*1024*1024)       // int8 [128][768][256] (dead after attn)
#define OFF_A2     (68L*1024*1024)       // int8 [25088][768]    (dead after fc1_vt)
#define OFF_A6     (44L*1024*1024)       // int8 [25088][3072]   (overlays A0T+A2)

__device__ __forceinline__ float rclipf(float v) {
  // clip(round_half_even(v), -128, 127) ; matches jnp.clip(jnp.round(x),-n,n-1)
  return fminf(fmaxf(rintf(v), -128.f), 127.f);
}

// ---------------- absmax over 9 weight tensors ----------------
__global__ void absmax_k(const float* p0, const float* p1, const float* p2,
                         const float* p3, const float* p4, const float* p5,
                         const float* p6, const float* p7, const float* p8,
                         float* amax) {
  int tsel = blockIdx.y;
  const float* src; int n;
  switch (tsel) {
    case 0: src = p0; n = 768;     break;  // norm1_a
    case 1: src = p1; n = N_*N_;   break;  // attn_w
    case 2: src = p2; n = 768;     break;  // gamma1
    case 3: src = p3; n = 768;     break;  // norm2_a
    case 4: src = p4; n = R_*D_;   break;  // fc1_vt_w
    case 5: src = p5; n = H_*R_;   break;  // fc1_u_w
    case 6: src = p6; n = R_*H_;   break;  // fc2_vt_w
    case 7: src = p7; n = D_*R_;   break;  // fc2_u_w
    default: src = p8; n = 768;    break;  // gamma2
  }
  float m = 0.f;
  for (int i = blockIdx.x*blockDim.x + threadIdx.x; i < n; i += gridDim.x*blockDim.x)
    m = fmaxf(m, fabsf(src[i]));
  #pragma unroll
  for (int off = 32; off > 0; off >>= 1)
    m = fmaxf(m, __shfl_down(m, off));
  if ((threadIdx.x & 63) == 0)
    atomicMax((int*)(amax + tsel), __float_as_int(m));  // non-negative floats: int order == float order
}

// ---------------- precompute epilogue vectors + GELU LUT (1 block, 768 thr) ----------------
// dst layout (floats): [0]=n1as=qn1a/s0  [768]=n1bs=n1b/s0  [1536]=g1s=s1*qg1/s8
//                      [2304]=a2s8=s8*qn2a/s2  [3072]=b2s=n2b/s2  [3840]=g2s9=s3*qg2/s9
__global__ void prep_vec_k(const float* n1a, const float* n1b, const float* g1,
                           const float* n2a, const float* n2b, const float* g2,
                           const float* amax, const float* actS, float* dst,
                           int8_t* lut) {
  int i = threadIdx.x;  // 768
  float s0 = actS[0], s1 = actS[1], s2 = actS[2], s3 = actS[3];
  float s8 = actS[8], s9 = actS[9];
  float sw;
  sw = amax[0]/127.f + 1e-8f; float qn1a = sw * rclipf(n1a[i]/sw);
  dst[i]        = qn1a / s0;
  dst[768+i]    = n1b[i] / s0;
  sw = amax[2]/127.f + 1e-8f; float qg1 = sw * rclipf(g1[i]/sw);
  dst[1536+i]   = (s1 * qg1) / s8;
  sw = amax[3]/127.f + 1e-8f; float qn2a = sw * rclipf(n2a[i]/sw);
  dst[2304+i]   = (s8 * qn2a) / s2;
  dst[3072+i]   = n2b[i] / s2;
  sw = amax[8]/127.f + 1e-8f; float qg2 = sw * rclipf(g2[i]/sw);
  dst[3840+i]   = (s3 * qg2) / s9;
  if (i < 256) {
    // GELU LUT: q5 (int8) -> q6 (int8), bit-identical to the erff reference chain
    float s5 = actS[5], s6 = actS[6];
    float v5 = s5 * (float)(i - 128);
    float g  = 0.5f * v5 * (1.f + erff(v5 * 0.70710678118654752f));
    lut[i] = (int8_t)(int)rclipf(g / s6);
  }
}

// ---------------- quantize all 5 matmul weights (blockIdx.y selects tensor) ----------------
__global__ void quant_all_k(const float* w1vt, const float* w1u, const float* w2vt,
                            const float* w2u, const float* attw, const float* amax,
                            int8_t* W1VT, int8_t* W1U, int8_t* W2VT, int8_t* W2U,
                            int8_t* WQA) {
  int sel = blockIdx.y;
  const float* src; int8_t* dst; int n; float am;
  switch (sel) {
    case 0: src = w1vt; dst = W1VT; n = R_*D_;  am = amax[4]; break;
    case 1: src = w1u;  dst = W1U;  n = H_*R_;  am = amax[5]; break;
    case 2: src = w2vt; dst = W2VT; n = R_*H_;  am = amax[6]; break;
    case 3: src = w2u;  dst = W2U;  n = D_*R_;  am = amax[7]; break;
    default: src = attw; dst = WQA; n = 65536;  am = amax[1]; break;
  }
  float s = am / 127.f + 1e-8f;
  if (sel < 4) {
    for (int i = blockIdx.x*blockDim.x + threadIdx.x; i < n; i += gridDim.x*blockDim.x)
      dst[i] = (int8_t)(int)rclipf(src[i] / s);
  } else {
    for (int i = blockIdx.x*blockDim.x + threadIdx.x; i < n; i += gridDim.x*blockDim.x) {
      int m = i >> 8, nn = i & 255;
      int8_t q = 0;
      if (m < N_ && nn < N_) q = (int8_t)(int)rclipf(attw[m*N_ + nn] / s);
      dst[i] = q;
    }
  }
}

// ---------------- stage A: norm1 affine + act-quant, transposed to A0T[b][d][n256] ----------------
__global__ void stageA_k(const float* __restrict__ x, const float* __restrict__ n1as,
                         const float* __restrict__ n1bs, int8_t* __restrict__ A0T) {
  __shared__ int8_t ldsT[64*68];   // [d][n] tile, pad 68 keeps u32 align + conflict-free
  const int dt = blockIdx.x;   // 0..11 (d tile of 64)
  const int nt = blockIdx.y;   // 0..3  (n tile of 64, n padded to 256)
  const int b  = blockIdx.z;
  const int d0 = dt*64, n0 = nt*64;
  const int tid = threadIdx.x;
  const int dc = tid & 63, nr4 = tid >> 6;
  const float qa = n1as[d0 + dc];
  const float bb = n1bs[d0 + dc];
  #pragma unroll 4
  for (int it = 0; it < 16; ++it) {
    int nl = nr4 + it*4;
    int n = n0 + nl;
    int8_t q = 0;
    if (n < N_) {
      float v = fmaf(x[((long)b*N_ + n)*D_ + d0 + dc], qa, bb);
      q = (int8_t)(int)rclipf(v);
    }
    ldsT[dc*68 + nl] = q;
  }
  __syncthreads();
  const int k = tid & 15, dr = tid >> 4;
  #pragma unroll
  for (int it = 0; it < 4; ++it) {
    int d = dr + it*16;
    uint32_t v = *(const uint32_t*)(&ldsT[d*68 + k*4]);
    *(uint32_t*)(&A0T[(long)b*(D_*256) + (long)(d0+d)*256 + n0 + k*4]) = v;
  }
}

// ---------------- generic i8 GEMM: Out[i,j] = sum_k A[i,k]*W[j,k] ----------------
// TRANSPOSED convention: A = weight matrix (rows = output features, i),
// W = activations (rows = tokens, j). MFMA C-layout reg r walks i -> packed
// 4-byte stores at out[j*ld + i], float4 for the fp32 final output.
// K-loop: m97 structure — global_load_lds(16B) direct-to-LDS, single buffer,
// unpadded [128][64] tiles, 2 barriers/kt. 16.4 KB LDS -> 5 blocks/CU.
// Epilogues: 0=attn(+gamma1+res+norm2+act3), 1=plain quant, 2=quant+LUT(GELU), 3=final.
struct GemmParams {
  const int8_t* A;
  const int8_t* W;
  int K, MT, NT;
  long batchStrideA;
  const float* actS;
  const float* amax;
  int amaxIdx, sInIdx, sOutIdx, sOut2Idx;
  const float* bias;     // indexed by i (EPI 1/2/3) or j (EPI 0)
  int8_t* out8;
  int ldOut;
  // attn epilogue (EPI=0): g1s / a2s8 / b2s vectors
  const float* xorg;
  const float* g1s;
  const float* a2s8;
  const float* b2s;
  int8_t* X1q;
  int8_t* A2;
  // final epilogue (EPI=3)
  const float* g2s9;
  const int8_t* X1qIn;
  float* outF;
  // EPI=2
  const int8_t* lutG;
};

template<int EPI>
__launch_bounds__(256, 5)
__global__ void gemm_i8(GemmParams p) {
  __shared__ __align__(16) int8_t lsA[128][64];   // unpadded: global_load_lds dest
  __shared__ __align__(16) int8_t lsB[128][64];
  __shared__ int8_t lut[256];
  const int K  = p.K;
  const int bx = blockIdx.x;
  const int mt = bx % p.MT;
  const int nt = bx / p.MT;
  const int t    = threadIdx.x;
  const int wid  = t >> 6;
  const int lane = t & 63;
  const int wm = wid & 1, wn = wid >> 1;
  const int quad = lane >> 4, l15 = lane & 15;

  if constexpr (EPI == 2) lut[t] = p.lutG[t];   // ordered by the first K-loop __syncthreads

  const int8_t* Abase = p.A + (long)blockIdx.y * p.batchStrideA + (long)mt*128*K;
  const int8_t* Wbase = p.W + (long)nt*128*K;

  // staging: thread t loads row t>>2 (+64), 16B chunk (t&3); LDS offset = t*16 (+4096)
  const int8_t* Ab = Abase + (long)(t >> 2)*K + (t & 3)*16;
  const int8_t* Bb = Wbase + (long)(t >> 2)*K + (t & 3)*16;
  const long half = 64L * K;
  int8_t* lsAf = &lsA[0][0];
  int8_t* lsBf = &lsB[0][0];

  const i32x4 zero = {0, 0, 0, 0};
  i32x4 acc[4][4];
  #pragma unroll
  for (int i = 0; i < 4; ++i)
    #pragma unroll
    for (int j = 0; j < 4; ++j) acc[i][j] = zero;

  const int KT = K >> 6;
  for (int kt = 0; kt < KT; ++kt) {
    const int k = kt << 6;
    GLDS16(Ab + k,        lsAf + t*16);
    GLDS16(Ab + half + k, lsAf + 4096 + t*16);
    GLDS16(Bb + k,        lsBf + t*16);
    GLDS16(Bb + half + k, lsBf + 4096 + t*16);
    __syncthreads();                       // compiler emits vmcnt(0) drain here
    i32x4 af[4], bf[4];
    #pragma unroll
    for (int i = 0; i < 4; ++i)
      af[i] = *(const i32x4*)(&lsA[wm*64 + i*16 + l15][quad*16]);
    #pragma unroll
    for (int j = 0; j < 4; ++j)
      bf[j] = *(const i32x4*)(&lsB[wn*64 + j*16 + l15][quad*16]);
    #pragma unroll
    for (int i = 0; i < 4; ++i)
      #pragma unroll
      for (int j = 0; j < 4; ++j)
        acc[i][j] = __builtin_amdgcn_mfma_i32_16x16x64_i8(af[i], bf[j], acc[i][j], 0, 0, 0);
    __syncthreads();                       // protect LDS before next tile's DMA
  }

  // ---- epilogue ---- C/D layout (16x16, m89-verified): col=lane&15, row=quad*4+reg
  const float sW  = p.amax[p.amaxIdx] / 127.f + 1e-8f;
  const float sAB = p.actS[p.sInIdx] * sW;
  const int i0 = mt*128 + wm*64;
  const int j0 = nt*128 + wn*64;

  #pragma unroll
  for (int ii = 0; ii < 4; ++ii) {
    const int i = i0 + ii*16 + quad*4;   // GEMM row (feature dim)
    if constexpr (EPI == 0) {
      // i = d (0..767), j = m patch (guard <196), batch = blockIdx.y
      const float c1     = sAB / p.actS[1];
      const float inv_s8 = 1.f / p.actS[8];
      const float4 g1s4 = *(const float4*)(p.g1s + i);
      const float4 a2s4 = *(const float4*)(p.a2s8 + i);
      const float4 b2s4 = *(const float4*)(p.b2s + i);
      #pragma unroll
      for (int jj = 0; jj < 4; ++jj) {
        const int j = j0 + jj*16 + l15;
        if (j < N_) {
          const float c2 = p.bias[j] / p.actS[1];
          const long tok = (long)blockIdx.y * N_ + j;
          const float4 xo = *(const float4*)(p.xorg + tok*D_ + i);
          uint32_t pk8 = 0, pk2 = 0;
          #pragma unroll
          for (int r = 0; r < 4; ++r) {
            float accf = (float)acc[ii][jj][r];
            float q1 = rclipf(fmaf(accf, c1, c2));                               // act2
            float q8 = rclipf(fmaf(q1, ((const float*)&g1s4)[r],
                                   ((const float*)&xo)[r] * inv_s8));            // gamma1 + res
            float q2 = rclipf(fmaf(q8, ((const float*)&a2s4)[r],
                                   ((const float*)&b2s4)[r]));                   // norm2 + act3
            pk8 |= ((uint32_t)(uint8_t)(int8_t)(int)q8) << (8*r);
            pk2 |= ((uint32_t)(uint8_t)(int8_t)(int)q2) << (8*r);
          }
          *(uint32_t*)(p.X1q + tok*D_ + i) = pk8;
          *(uint32_t*)(p.A2  + tok*D_ + i) = pk2;
        }
      }
    } else if constexpr (EPI == 1) {
      const float sO = p.actS[p.sOutIdx];
      const float c1 = sAB / sO;
      const float4 b4 = *(const float4*)(p.bias + i);
      float c2[4];
      #pragma unroll
      for (int r = 0; r < 4; ++r) c2[r] = ((const float*)&b4)[r] / sO;
      #pragma unroll
      for (int jj = 0; jj < 4; ++jj) {
        const int j = j0 + jj*16 + l15;
        uint32_t pk = 0;
        #pragma unroll
        for (int r = 0; r < 4; ++r) {
          float q = rclipf(fmaf((float)acc[ii][jj][r], c1, c2[r]));
          pk |= ((uint32_t)(uint8_t)(int8_t)(int)q) << (8*r);
        }
        *(uint32_t*)(p.out8 + (long)j*p.ldOut + i) = pk;
      }
    } else if constexpr (EPI == 2) {
      const float s5v = p.actS[p.sOutIdx];
      const float c1 = sAB / s5v;
      const float4 b4 = *(const float4*)(p.bias + i);
      float c2[4];
      #pragma unroll
      for (int r = 0; r < 4; ++r) c2[r] = ((const float*)&b4)[r] / s5v;
      #pragma unroll
      for (int jj = 0; jj < 4; ++jj) {
        const int j = j0 + jj*16 + l15;
        uint32_t pk = 0;
        #pragma unroll
        for (int r = 0; r < 4; ++r) {
          int q5 = (int)rclipf(fmaf((float)acc[ii][jj][r], c1, c2[r])) + 128;  // act2 idx
          pk |= ((uint32_t)(uint8_t)lut[q5]) << (8*r);                         // GELU+act3
        }
        *(uint32_t*)(p.out8 + (long)j*p.ldOut + i) = pk;
      }
    } else {
      const float s3v = p.actS[3], s9v = p.actS[9];
      const float c1  = sAB / s3v;
      const float c89 = p.actS[8] / s9v;
      const float4 b4 = *(const float4*)(p.bias + i);
      const float4 g4 = *(const float4*)(p.g2s9 + i);
      float c2[4];
      #pragma unroll
      for (int r = 0; r < 4; ++r) c2[r] = ((const float*)&b4)[r] / s3v;
      #pragma unroll
      for (int jj = 0; jj < 4; ++jj) {
        const int j = j0 + jj*16 + l15;
        const uint32_t pk8 = *(const uint32_t*)(p.X1qIn + (long)j*D_ + i);
        float4 o;
        #pragma unroll
        for (int r = 0; r < 4; ++r) {
          float q3 = rclipf(fmaf((float)acc[ii][jj][r], c1, c2[r]));   // block act4
          float q8 = (float)(int8_t)(uint8_t)(pk8 >> (8*r));
          float q9 = rclipf(fmaf(q3, ((const float*)&g4)[r], q8 * c89)); // gamma2+res+add_2
          ((float*)&o)[r] = s9v * q9;
        }
        *(float4*)(p.outF + (long)j*D_ + i) = o;
      }
    }
  }
}

// ---------------- host launch ----------------
extern "C" void kernel_launch(void* const* d_in, const int* in_sizes, int n_in,
                              void* d_out, int out_size, void* d_ws, size_t ws_size,
                              hipStream_t stream) {
  (void)in_sizes; (void)n_in; (void)out_size; (void)ws_size;
  const float* x    = (const float*)d_in[0];
  const float* n1a  = (const float*)d_in[1];
  const float* n1b  = (const float*)d_in[2];
  const float* attw = (const float*)d_in[3];
  const float* attb = (const float*)d_in[4];
  const float* g1   = (const float*)d_in[5];
  const float* n2a  = (const float*)d_in[6];
  const float* n2b  = (const float*)d_in[7];
  const float* w1vt = (const float*)d_in[8];
  const float* b1vt = (const float*)d_in[9];
  const float* w1u  = (const float*)d_in[10];
  const float* b1u  = (const float*)d_in[11];
  const float* w2vt = (const float*)d_in[12];
  const float* b2vt = (const float*)d_in[13];
  const float* w2u  = (const float*)d_in[14];
  const float* b2u  = (const float*)d_in[15];
  const float* g2   = (const float*)d_in[16];
  const float* actS = (const float*)d_in[17];
  float* out = (float*)d_out;
  char* ws = (char*)d_ws;

  float*  amax = (float*)(ws + OFF_AMAX);
  int8_t* LUTG = (int8_t*)(ws + OFF_LUT);
  float*  qvec = (float*)(ws + OFF_QVEC);
  int8_t* WQA  = (int8_t*)(ws + OFF_WQA);
  int8_t* W1VT = (int8_t*)(ws + OFF_W1VT);
  int8_t* W1U  = (int8_t*)(ws + OFF_W1U);
  int8_t* W2VT = (int8_t*)(ws + OFF_W2VT);
  int8_t* W2U  = (int8_t*)(ws + OFF_W2U);
  int8_t* X1Q  = (int8_t*)(ws + OFF_X1Q);
  int8_t* A4   = (int8_t*)(ws + OFF_A4);
  int8_t* A7   = (int8_t*)(ws + OFF_A7);
  int8_t* A0T  = (int8_t*)(ws + OFF_A0T);
  int8_t* A2   = (int8_t*)(ws + OFF_A2);
  int8_t* A6   = (int8_t*)(ws + OFF_A6);

  hipMemsetAsync(amax, 0, 64, stream);
  absmax_k<<<dim3(32, 9), 256, 0, stream>>>(n1a, attw, g1, n2a, w1vt, w1u, w2vt, w2u, g2, amax);
  prep_vec_k<<<1, 768, 0, stream>>>(n1a, n1b, g1, n2a, n2b, g2, amax, actS, qvec, LUTG);
  quant_all_k<<<dim3(1152, 5), 256, 0, stream>>>(w1vt, w1u, w2vt, w2u, attw, amax,
                                                 W1VT, W1U, W2VT, W2U, WQA);
  stageA_k<<<dim3(12, 4, 128), 256, 0, stream>>>(x, qvec, qvec + 768, A0T);

  // attn: per-batch Out[d,m] = sum_n A0T[b][d][n] * WQA[m][n]; fused through act3
  GemmParams pa = {};
  pa.A = A0T; pa.W = WQA; pa.K = 256; pa.MT = 6; pa.NT = 2;
  pa.batchStrideA = (long)D_*256;
  pa.actS = actS; pa.amax = amax; pa.amaxIdx = 1; pa.sInIdx = 0;
  pa.bias = attb; pa.xorg = x;
  pa.g1s = qvec + 1536; pa.a2s8 = qvec + 2304; pa.b2s = qvec + 3072;
  pa.X1q = X1Q; pa.A2 = A2;
  gemm_i8<0><<<dim3(12, 128), 256, 0, stream>>>(pa);

  // fc1_VT (transposed): A=W1VT [384][768], W=A2 [25088][768] -> A4 [tok][384]
  GemmParams p1 = {};
  p1.A = W1VT; p1.W = A2; p1.K = D_; p1.MT = R_/128; p1.NT = TOK/128;
  p1.actS = actS; p1.amax = amax; p1.amaxIdx = 4; p1.sInIdx = 2; p1.sOutIdx = 4;
  p1.bias = b1vt; p1.out8 = A4; p1.ldOut = R_;
  gemm_i8<1><<<dim3((R_/128)*(TOK/128)), 256, 0, stream>>>(p1);

  // fc1_U (transposed): A=W1U [3072][384], W=A4 [tok][384] -> q5->GELU(LUT)->q6 -> A6 [tok][3072]
  GemmParams p2 = {};
  p2.A = W1U; p2.W = A4; p2.K = R_; p2.MT = H_/128; p2.NT = TOK/128;
  p2.actS = actS; p2.amax = amax; p2.amaxIdx = 5; p2.sInIdx = 4; p2.sOutIdx = 5; p2.sOut2Idx = 6;
  p2.bias = b1u; p2.out8 = A6; p2.ldOut = H_; p2.lutG = LUTG;
  gemm_i8<2><<<dim3((H_/128)*(TOK/128)), 256, 0, stream>>>(p2);

  // fc2_VT (transposed): A=W2VT [384][3072], W=A6 [tok][3072] -> A7 [tok][384]
  GemmParams p3 = {};
  p3.A = W2VT; p3.W = A6; p3.K = H_; p3.MT = R_/128; p3.NT = TOK/128;
  p3.actS = actS; p3.amax = amax; p3.amaxIdx = 6; p3.sInIdx = 6; p3.sOutIdx = 7;
  p3.bias = b2vt; p3.out8 = A7; p3.ldOut = R_;
  gemm_i8<1><<<dim3((R_/128)*(TOK/128)), 256, 0, stream>>>(p3);

  // fc2_U (transposed): A=W2U [768][384], W=A7 [tok][384] -> q3->gamma2->+x1->q9 -> out fp32
  GemmParams p4 = {};
  p4.A = W2U; p4.W = A7; p4.K = R_; p4.MT = D_/128; p4.NT = TOK/128;
  p4.actS = actS; p4.amax = amax; p4.amaxIdx = 7; p4.sInIdx = 7;
  p4.bias = b2u; p4.g2s9 = qvec + 3840; p4.X1qIn = X1Q; p4.outF = out; p4.ldOut = D_;
  gemm_i8<3><<<dim3((D_/128)*(TOK/128)), 256, 0, stream>>>(p4);
}

// Round 6
// 508.751 us; speedup vs baseline: 1.0593x; 1.0593x over previous
//
#include <hip/hip_runtime.h>
#include <cstdint>
#include <cmath>

// Problem dims
#define B_   128
#define N_   196
#define D_   768
#define H_   3072
#define R_   384
#define TOK  (B_*N_)      // 25088

typedef int i32x4 __attribute__((ext_vector_type(4)));

// async global->LDS, 16B per lane; LDS dest = wave-uniform base + lane*16
#define GLDS16(g, l) __builtin_amdgcn_global_load_lds( \
    (const __attribute__((address_space(1))) void*)(g), \
    (__attribute__((address_space(3))) void*)(l), 16, 0, 0)

// s_waitcnt imm (gfx9): vmcnt[3:0], expcnt[6:4]=7, lgkmcnt[11:8]=15, vmcnt hi[15:14]=0
#define WAITV4() __builtin_amdgcn_s_waitcnt(0xF74)   // vmcnt(4)
#define WAITV0() __builtin_amdgcn_s_waitcnt(0xF70)   // vmcnt(0)
#define BARRIER() do { __asm__ volatile("" ::: "memory"); \
                       __builtin_amdgcn_s_barrier(); \
                       __asm__ volatile("" ::: "memory"); } while (0)

// ---------------- workspace layout (bytes) ----------------
#define OFF_AMAX   0L
#define OFF_LUT    512L                  // 256-entry int8 GELU LUT
#define OFF_QVEC   1024L                 // 6 x 768 fp32 precomputed epilogue vectors
#define OFF_WQA    (32L*1024)            // attn weight int8 padded [256][256]
#define OFF_W1VT   (128L*1024)           // [384][768]
#define OFF_W1U    (512L*1024)           // [3072][384]
#define OFF_W2VT   (2L*1024*1024)        // [384][3072]
#define OFF_W2U    (3328L*1024)          // [768][384]
#define OFF_X1Q    (4L*1024*1024)        // int8 [25088][768]
#define OFF_A4     (24L*1024*1024)       // int8 [25088][384]
#define OFF_A7     (34L*1024*1024)       // int8 [25088][384]
#define OFF_A0T    (44L*1024*1024)       // int8 [128][768][256] (dead after attn)
#define OFF_A2     (68L*1024*1024)       // int8 [25088][768]    (dead after fc1_vt)
#define OFF_A6     (44L*1024*1024)       // int8 [25088][3072]   (overlays A0T+A2)

__device__ __forceinline__ float rclipf(float v) {
  // clip(round_half_even(v), -128, 127) ; matches jnp.clip(jnp.round(x),-n,n-1)
  return fminf(fmaxf(rintf(v), -128.f), 127.f);
}

// ---------------- absmax over 9 weight tensors ----------------
__global__ void absmax_k(const float* p0, const float* p1, const float* p2,
                         const float* p3, const float* p4, const float* p5,
                         const float* p6, const float* p7, const float* p8,
                         float* amax) {
  int tsel = blockIdx.y;
  const float* src; int n;
  switch (tsel) {
    case 0: src = p0; n = 768;     break;  // norm1_a
    case 1: src = p1; n = N_*N_;   break;  // attn_w
    case 2: src = p2; n = 768;     break;  // gamma1
    case 3: src = p3; n = 768;     break;  // norm2_a
    case 4: src = p4; n = R_*D_;   break;  // fc1_vt_w
    case 5: src = p5; n = H_*R_;   break;  // fc1_u_w
    case 6: src = p6; n = R_*H_;   break;  // fc2_vt_w
    case 7: src = p7; n = D_*R_;   break;  // fc2_u_w
    default: src = p8; n = 768;    break;  // gamma2
  }
  float m = 0.f;
  for (int i = blockIdx.x*blockDim.x + threadIdx.x; i < n; i += gridDim.x*blockDim.x)
    m = fmaxf(m, fabsf(src[i]));
  #pragma unroll
  for (int off = 32; off > 0; off >>= 1)
    m = fmaxf(m, __shfl_down(m, off));
  if ((threadIdx.x & 63) == 0)
    atomicMax((int*)(amax + tsel), __float_as_int(m));  // non-negative floats: int order == float order
}

// ---------------- precompute epilogue vectors + GELU LUT (1 block, 768 thr) ----------------
// dst layout (floats): [0]=n1as=qn1a/s0  [768]=n1bs=n1b/s0  [1536]=g1s=s1*qg1/s8
//                      [2304]=a2s8=s8*qn2a/s2  [3072]=b2s=n2b/s2  [3840]=g2s9=s3*qg2/s9
__global__ void prep_vec_k(const float* n1a, const float* n1b, const float* g1,
                           const float* n2a, const float* n2b, const float* g2,
                           const float* amax, const float* actS, float* dst,
                           int8_t* lut) {
  int i = threadIdx.x;  // 768
  float s0 = actS[0], s1 = actS[1], s2 = actS[2], s3 = actS[3];
  float s8 = actS[8], s9 = actS[9];
  float sw;
  sw = amax[0]/127.f + 1e-8f; float qn1a = sw * rclipf(n1a[i]/sw);
  dst[i]        = qn1a / s0;
  dst[768+i]    = n1b[i] / s0;
  sw = amax[2]/127.f + 1e-8f; float qg1 = sw * rclipf(g1[i]/sw);
  dst[1536+i]   = (s1 * qg1) / s8;
  sw = amax[3]/127.f + 1e-8f; float qn2a = sw * rclipf(n2a[i]/sw);
  dst[2304+i]   = (s8 * qn2a) / s2;
  dst[3072+i]   = n2b[i] / s2;
  sw = amax[8]/127.f + 1e-8f; float qg2 = sw * rclipf(g2[i]/sw);
  dst[3840+i]   = (s3 * qg2) / s9;
  if (i < 256) {
    // GELU LUT: q5 (int8) -> q6 (int8), bit-identical to the erff reference chain
    float s5 = actS[5], s6 = actS[6];
    float v5 = s5 * (float)(i - 128);
    float g  = 0.5f * v5 * (1.f + erff(v5 * 0.70710678118654752f));
    lut[i] = (int8_t)(int)rclipf(g / s6);
  }
}

// ---------------- quantize all 5 matmul weights (blockIdx.y selects tensor) ----------------
__global__ void quant_all_k(const float* w1vt, const float* w1u, const float* w2vt,
                            const float* w2u, const float* attw, const float* amax,
                            int8_t* W1VT, int8_t* W1U, int8_t* W2VT, int8_t* W2U,
                            int8_t* WQA) {
  int sel = blockIdx.y;
  const float* src; int8_t* dst; int n; float am;
  switch (sel) {
    case 0: src = w1vt; dst = W1VT; n = R_*D_;  am = amax[4]; break;
    case 1: src = w1u;  dst = W1U;  n = H_*R_;  am = amax[5]; break;
    case 2: src = w2vt; dst = W2VT; n = R_*H_;  am = amax[6]; break;
    case 3: src = w2u;  dst = W2U;  n = D_*R_;  am = amax[7]; break;
    default: src = attw; dst = WQA; n = 65536;  am = amax[1]; break;
  }
  float s = am / 127.f + 1e-8f;
  if (sel < 4) {
    for (int i = blockIdx.x*blockDim.x + threadIdx.x; i < n; i += gridDim.x*blockDim.x)
      dst[i] = (int8_t)(int)rclipf(src[i] / s);
  } else {
    for (int i = blockIdx.x*blockDim.x + threadIdx.x; i < n; i += gridDim.x*blockDim.x) {
      int m = i >> 8, nn = i & 255;
      int8_t q = 0;
      if (m < N_ && nn < N_) q = (int8_t)(int)rclipf(attw[m*N_ + nn] / s);
      dst[i] = q;
    }
  }
}

// ---------------- stage A: norm1 affine + act-quant, transposed to A0T[b][d][n256] ----------------
__global__ void stageA_k(const float* __restrict__ x, const float* __restrict__ n1as,
                         const float* __restrict__ n1bs, int8_t* __restrict__ A0T) {
  __shared__ int8_t ldsT[64*68];   // [d][n] tile, pad 68 keeps u32 align + conflict-free
  const int dt = blockIdx.x;   // 0..11 (d tile of 64)
  const int nt = blockIdx.y;   // 0..3  (n tile of 64, n padded to 256)
  const int b  = blockIdx.z;
  const int d0 = dt*64, n0 = nt*64;
  const int tid = threadIdx.x;
  const int dc = tid & 63, nr4 = tid >> 6;
  const float qa = n1as[d0 + dc];
  const float bb = n1bs[d0 + dc];
  #pragma unroll 4
  for (int it = 0; it < 16; ++it) {
    int nl = nr4 + it*4;
    int n = n0 + nl;
    int8_t q = 0;
    if (n < N_) {
      float v = fmaf(x[((long)b*N_ + n)*D_ + d0 + dc], qa, bb);
      q = (int8_t)(int)rclipf(v);
    }
    ldsT[dc*68 + nl] = q;
  }
  __syncthreads();
  const int k = tid & 15, dr = tid >> 4;
  #pragma unroll
  for (int it = 0; it < 4; ++it) {
    int d = dr + it*16;
    uint32_t v = *(const uint32_t*)(&ldsT[d*68 + k*4]);
    *(uint32_t*)(&A0T[(long)b*(D_*256) + (long)(d0+d)*256 + n0 + k*4]) = v;
  }
}

// ---------------- generic i8 GEMM: Out[i,j] = sum_k A[i,k]*W[j,k] ----------------
// TRANSPOSED convention: A = weight matrix (rows = output features, i),
// W = activations (rows = tokens, j). MFMA C-layout reg r walks i -> packed
// 4-byte stores at out[j*ld + i], float4 for the fp32 final output.
// K-loop: DOUBLE-buffered global_load_lds with fine-grained vmcnt —
//   issue DMA(kt+1) -> buf^1, s_waitcnt vmcnt(4) (tile kt landed, kt+1 still
//   in flight), raw s_barrier (no drain), compute, raw s_barrier.
//   This keeps the prefetch alive across the barrier (CK block_sync_lds style).
// Epilogues: 0=attn(+gamma1+res+norm2+act3), 1=plain quant, 2=quant+LUT(GELU), 3=final.
struct GemmParams {
  const int8_t* A;
  const int8_t* W;
  int K, MT, NT;
  long batchStrideA;
  const float* actS;
  const float* amax;
  int amaxIdx, sInIdx, sOutIdx, sOut2Idx;
  const float* bias;     // indexed by i (EPI 1/2/3) or j (EPI 0)
  int8_t* out8;
  int ldOut;
  // attn epilogue (EPI=0): g1s / a2s8 / b2s vectors
  const float* xorg;
  const float* g1s;
  const float* a2s8;
  const float* b2s;
  int8_t* X1q;
  int8_t* A2;
  // final epilogue (EPI=3)
  const float* g2s9;
  const int8_t* X1qIn;
  float* outF;
  // EPI=2
  const int8_t* lutG;
};

template<int EPI>
__launch_bounds__(256, 4)
__global__ void gemm_i8(GemmParams p) {
  __shared__ __align__(16) int8_t lsA[2][128][64];   // unpadded: global_load_lds dest
  __shared__ __align__(16) int8_t lsB[2][128][64];
  __shared__ int8_t lut[256];
  const int K  = p.K;
  const int bx = blockIdx.x;
  const int mt = bx % p.MT;
  const int nt = bx / p.MT;
  const int t    = threadIdx.x;
  const int wid  = t >> 6;
  const int lane = t & 63;
  const int wm = wid & 1, wn = wid >> 1;
  const int quad = lane >> 4, l15 = lane & 15;

  if constexpr (EPI == 2) lut[t] = p.lutG[t];   // visible after first K-loop barrier

  const int8_t* Abase = p.A + (long)blockIdx.y * p.batchStrideA + (long)mt*128*K;
  const int8_t* Wbase = p.W + (long)nt*128*K;

  // staging: thread t loads row t>>2 (+64), 16B chunk (t&3); LDS offset = t*16 (+4096)
  const int8_t* Ab = Abase + (long)(t >> 2)*K + (t & 3)*16;
  const int8_t* Bb = Wbase + (long)(t >> 2)*K + (t & 3)*16;
  const long half = 64L * K;

  auto issue = [&](int kt) {
    const int buf = kt & 1;
    const long k = (long)kt << 6;
    GLDS16(Ab + k,        &lsA[buf][0][0]  + t*16);
    GLDS16(Ab + half + k, &lsA[buf][64][0] + t*16);
    GLDS16(Bb + k,        &lsB[buf][0][0]  + t*16);
    GLDS16(Bb + half + k, &lsB[buf][64][0] + t*16);
  };

  const i32x4 zero = {0, 0, 0, 0};
  i32x4 acc[4][4];
  #pragma unroll
  for (int i = 0; i < 4; ++i)
    #pragma unroll
    for (int j = 0; j < 4; ++j) acc[i][j] = zero;

  const int KT = K >> 6;
  issue(0);
  for (int kt = 0; kt < KT; ++kt) {
    const int cur = kt & 1;
    if (kt + 1 < KT) { issue(kt + 1); WAITV4(); }   // tile kt resident; kt+1 in flight
    else             { WAITV0(); }
    BARRIER();                                       // all threads' tile-kt chunks visible
    i32x4 af[4], bf[4];
    #pragma unroll
    for (int i = 0; i < 4; ++i)
      af[i] = *(const i32x4*)(&lsA[cur][wm*64 + i*16 + l15][quad*16]);
    #pragma unroll
    for (int j = 0; j < 4; ++j)
      bf[j] = *(const i32x4*)(&lsB[cur][wn*64 + j*16 + l15][quad*16]);
    #pragma unroll
    for (int i = 0; i < 4; ++i)
      #pragma unroll
      for (int j = 0; j < 4; ++j)
        acc[i][j] = __builtin_amdgcn_mfma_i32_16x16x64_i8(af[i], bf[j], acc[i][j], 0, 0, 0);
    BARRIER();                                       // reads done before buf's next DMA
  }

  // ---- epilogue ---- C/D layout (16x16, m89-verified): col=lane&15, row=quad*4+reg
  const float sW  = p.amax[p.amaxIdx] / 127.f + 1e-8f;
  const float sAB = p.actS[p.sInIdx] * sW;
  const int i0 = mt*128 + wm*64;
  const int j0 = nt*128 + wn*64;

  #pragma unroll
  for (int ii = 0; ii < 4; ++ii) {
    const int i = i0 + ii*16 + quad*4;   // GEMM row (feature dim)
    if constexpr (EPI == 0) {
      // i = d (0..767), j = m patch (guard <196), batch = blockIdx.y
      const float c1     = sAB / p.actS[1];
      const float inv_s8 = 1.f / p.actS[8];
      const float4 g1s4 = *(const float4*)(p.g1s + i);
      const float4 a2s4 = *(const float4*)(p.a2s8 + i);
      const float4 b2s4 = *(const float4*)(p.b2s + i);
      #pragma unroll
      for (int jj = 0; jj < 4; ++jj) {
        const int j = j0 + jj*16 + l15;
        if (j < N_) {
          const float c2 = p.bias[j] / p.actS[1];
          const long tok = (long)blockIdx.y * N_ + j;
          const float4 xo = *(const float4*)(p.xorg + tok*D_ + i);
          uint32_t pk8 = 0, pk2 = 0;
          #pragma unroll
          for (int r = 0; r < 4; ++r) {
            float accf = (float)acc[ii][jj][r];
            float q1 = rclipf(fmaf(accf, c1, c2));                               // act2
            float q8 = rclipf(fmaf(q1, ((const float*)&g1s4)[r],
                                   ((const float*)&xo)[r] * inv_s8));            // gamma1 + res
            float q2 = rclipf(fmaf(q8, ((const float*)&a2s4)[r],
                                   ((const float*)&b2s4)[r]));                   // norm2 + act3
            pk8 |= ((uint32_t)(uint8_t)(int8_t)(int)q8) << (8*r);
            pk2 |= ((uint32_t)(uint8_t)(int8_t)(int)q2) << (8*r);
          }
          *(uint32_t*)(p.X1q + tok*D_ + i) = pk8;
          *(uint32_t*)(p.A2  + tok*D_ + i) = pk2;
        }
      }
    } else if constexpr (EPI == 1) {
      const float sO = p.actS[p.sOutIdx];
      const float c1 = sAB / sO;
      const float4 b4 = *(const float4*)(p.bias + i);
      float c2[4];
      #pragma unroll
      for (int r = 0; r < 4; ++r) c2[r] = ((const float*)&b4)[r] / sO;
      #pragma unroll
      for (int jj = 0; jj < 4; ++jj) {
        const int j = j0 + jj*16 + l15;
        uint32_t pk = 0;
        #pragma unroll
        for (int r = 0; r < 4; ++r) {
          float q = rclipf(fmaf((float)acc[ii][jj][r], c1, c2[r]));
          pk |= ((uint32_t)(uint8_t)(int8_t)(int)q) << (8*r);
        }
        *(uint32_t*)(p.out8 + (long)j*p.ldOut + i) = pk;
      }
    } else if constexpr (EPI == 2) {
      const float s5v = p.actS[p.sOutIdx];
      const float c1 = sAB / s5v;
      const float4 b4 = *(const float4*)(p.bias + i);
      float c2[4];
      #pragma unroll
      for (int r = 0; r < 4; ++r) c2[r] = ((const float*)&b4)[r] / s5v;
      #pragma unroll
      for (int jj = 0; jj < 4; ++jj) {
        const int j = j0 + jj*16 + l15;
        uint32_t pk = 0;
        #pragma unroll
        for (int r = 0; r < 4; ++r) {
          int q5 = (int)rclipf(fmaf((float)acc[ii][jj][r], c1, c2[r])) + 128;  // act2 idx
          pk |= ((uint32_t)(uint8_t)lut[q5]) << (8*r);                         // GELU+act3
        }
        *(uint32_t*)(p.out8 + (long)j*p.ldOut + i) = pk;
      }
    } else {
      const float s3v = p.actS[3], s9v = p.actS[9];
      const float c1  = sAB / s3v;
      const float c89 = p.actS[8] / s9v;
      const float4 b4 = *(const float4*)(p.bias + i);
      const float4 g4 = *(const float4*)(p.g2s9 + i);
      float c2[4];
      #pragma unroll
      for (int r = 0; r < 4; ++r) c2[r] = ((const float*)&b4)[r] / s3v;
      #pragma unroll
      for (int jj = 0; jj < 4; ++jj) {
        const int j = j0 + jj*16 + l15;
        const uint32_t pk8 = *(const uint32_t*)(p.X1qIn + (long)j*D_ + i);
        float4 o;
        #pragma unroll
        for (int r = 0; r < 4; ++r) {
          float q3 = rclipf(fmaf((float)acc[ii][jj][r], c1, c2[r]));   // block act4
          float q8 = (float)(int8_t)(uint8_t)(pk8 >> (8*r));
          float q9 = rclipf(fmaf(q3, ((const float*)&g4)[r], q8 * c89)); // gamma2+res+add_2
          ((float*)&o)[r] = s9v * q9;
        }
        *(float4*)(p.outF + (long)j*D_ + i) = o;
      }
    }
  }
}

// ---------------- host launch ----------------
extern "C" void kernel_launch(void* const* d_in, const int* in_sizes, int n_in,
                              void* d_out, int out_size, void* d_ws, size_t ws_size,
                              hipStream_t stream) {
  (void)in_sizes; (void)n_in; (void)out_size; (void)ws_size;
  const float* x    = (const float*)d_in[0];
  const float* n1a  = (const float*)d_in[1];
  const float* n1b  = (const float*)d_in[2];
  const float* attw = (const float*)d_in[3];
  const float* attb = (const float*)d_in[4];
  const float* g1   = (const float*)d_in[5];
  const float* n2a  = (const float*)d_in[6];
  const float* n2b  = (const float*)d_in[7];
  const float* w1vt = (const float*)d_in[8];
  const float* b1vt = (const float*)d_in[9];
  const float* w1u  = (const float*)d_in[10];
  const float* b1u  = (const float*)d_in[11];
  const float* w2vt = (const float*)d_in[12];
  const float* b2vt = (const float*)d_in[13];
  const float* w2u  = (const float*)d_in[14];
  const float* b2u  = (const float*)d_in[15];
  const float* g2   = (const float*)d_in[16];
  const float* actS = (const float*)d_in[17];
  float* out = (float*)d_out;
  char* ws = (char*)d_ws;

  float*  amax = (float*)(ws + OFF_AMAX);
  int8_t* LUTG = (int8_t*)(ws + OFF_LUT);
  float*  qvec = (float*)(ws + OFF_QVEC);
  int8_t* WQA  = (int8_t*)(ws + OFF_WQA);
  int8_t* W1VT = (int8_t*)(ws + OFF_W1VT);
  int8_t* W1U  = (int8_t*)(ws + OFF_W1U);
  int8_t* W2VT = (int8_t*)(ws + OFF_W2VT);
  int8_t* W2U  = (int8_t*)(ws + OFF_W2U);
  int8_t* X1Q  = (int8_t*)(ws + OFF_X1Q);
  int8_t* A4   = (int8_t*)(ws + OFF_A4);
  int8_t* A7   = (int8_t*)(ws + OFF_A7);
  int8_t* A0T  = (int8_t*)(ws + OFF_A0T);
  int8_t* A2   = (int8_t*)(ws + OFF_A2);
  int8_t* A6   = (int8_t*)(ws + OFF_A6);

  hipMemsetAsync(amax, 0, 64, stream);
  absmax_k<<<dim3(32, 9), 256, 0, stream>>>(n1a, attw, g1, n2a, w1vt, w1u, w2vt, w2u, g2, amax);
  prep_vec_k<<<1, 768, 0, stream>>>(n1a, n1b, g1, n2a, n2b, g2, amax, actS, qvec, LUTG);
  quant_all_k<<<dim3(1152, 5), 256, 0, stream>>>(w1vt, w1u, w2vt, w2u, attw, amax,
                                                 W1VT, W1U, W2VT, W2U, WQA);
  stageA_k<<<dim3(12, 4, 128), 256, 0, stream>>>(x, qvec, qvec + 768, A0T);

  // attn: per-batch Out[d,m] = sum_n A0T[b][d][n] * WQA[m][n]; fused through act3
  GemmParams pa = {};
  pa.A = A0T; pa.W = WQA; pa.K = 256; pa.MT = 6; pa.NT = 2;
  pa.batchStrideA = (long)D_*256;
  pa.actS = actS; pa.amax = amax; pa.amaxIdx = 1; pa.sInIdx = 0;
  pa.bias = attb; pa.xorg = x;
  pa.g1s = qvec + 1536; pa.a2s8 = qvec + 2304; pa.b2s = qvec + 3072;
  pa.X1q = X1Q; pa.A2 = A2;
  gemm_i8<0><<<dim3(12, 128), 256, 0, stream>>>(pa);

  // fc1_VT (transposed): A=W1VT [384][768], W=A2 [25088][768] -> A4 [tok][384]
  GemmParams p1 = {};
  p1.A = W1VT; p1.W = A2; p1.K = D_; p1.MT = R_/128; p1.NT = TOK/128;
  p1.actS = actS; p1.amax = amax; p1.amaxIdx = 4; p1.sInIdx = 2; p1.sOutIdx = 4;
  p1.bias = b1vt; p1.out8 = A4; p1.ldOut = R_;
  gemm_i8<1><<<dim3((R_/128)*(TOK/128)), 256, 0, stream>>>(p1);

  // fc1_U (transposed): A=W1U [3072][384], W=A4 [tok][384] -> q5->GELU(LUT)->q6 -> A6 [tok][3072]
  GemmParams p2 = {};
  p2.A = W1U; p2.W = A4; p2.K = R_; p2.MT = H_/128; p2.NT = TOK/128;
  p2.actS = actS; p2.amax = amax; p2.amaxIdx = 5; p2.sInIdx = 4; p2.sOutIdx = 5; p2.sOut2Idx = 6;
  p2.bias = b1u; p2.out8 = A6; p2.ldOut = H_; p2.lutG = LUTG;
  gemm_i8<2><<<dim3((H_/128)*(TOK/128)), 256, 0, stream>>>(p2);

  // fc2_VT (transposed): A=W2VT [384][3072], W=A6 [tok][3072] -> A7 [tok][384]
  GemmParams p3 = {};
  p3.A = W2VT; p3.W = A6; p3.K = H_; p3.MT = R_/128; p3.NT = TOK/128;
  p3.actS = actS; p3.amax = amax; p3.amaxIdx = 6; p3.sInIdx = 6; p3.sOutIdx = 7;
  p3.bias = b2vt; p3.out8 = A7; p3.ldOut = R_;
  gemm_i8<1><<<dim3((R_/128)*(TOK/128)), 256, 0, stream>>>(p3);

  // fc2_U (transposed): A=W2U [768][384], W=A7 [tok][384] -> q3->gamma2->+x1->q9 -> out fp32
  GemmParams p4 = {};
  p4.A = W2U; p4.W = A7; p4.K = R_; p4.MT = D_/128; p4.NT = TOK/128;
  p4.actS = actS; p4.amax = amax; p4.amaxIdx = 7; p4.sInIdx = 7;
  p4.bias = b2u; p4.g2s9 = qvec + 3840; p4.X1qIn = X1Q; p4.outF = out; p4.ldOut = D_;
  gemm_i8<3><<<dim3((D_/128)*(TOK/128)), 256, 0, stream>>>(p4);
}